// Round 13
// baseline (85.579 us; speedup 1.0000x reference)
//
#include <hip/hip_runtime.h>

#define N_NODES 100000
#define D_FEAT 128
#define CLASSES 64
#define N_EDGES 800000
#define DUMMY N_NODES        // zero row in Y table
#define NPP 64               // nodes per partition
#define NPART 1563           // ceil(N_NODES / NPP)
#define NSUBQ (NPART * 8)    // 12504 sub-queues (8 XCDs)
#define QCAP 128             // per-sub-queue cap: mean 64, +8 sigma
#define ENT_CAP 768          // per-partition cap: mean 512, +11 sigma
#define QB_BLOCKS 1024
#define GEMM_BLOCKS 782      // ceil((NSTRIP/2)/4): 2 strips per wave
#define NSTRIP (N_NODES / 16)  // 6250

typedef short bf16x8 __attribute__((ext_vector_type(8)));
typedef float f32x4 __attribute__((ext_vector_type(4)));
typedef float fvec4 __attribute__((ext_vector_type(4)));

static __device__ __forceinline__ unsigned short f32_to_bf16(float f) {
    unsigned int u = __float_as_uint(f);
    u += 0x7FFFu + ((u >> 16) & 1u);  // round-to-nearest-even
    return (unsigned short)(u >> 16);
}
static __device__ __forceinline__ float bf16_lo(unsigned int u) {
    return __uint_as_float(u << 16);
}
static __device__ __forceinline__ float bf16_hi(unsigned int u) {
    return __uint_as_float(u & 0xFFFF0000u);
}

// Kernel 1: zero sub-queue tails (one counter per 64B line) + dummy Y row.
__global__ void zq_kernel(int* __restrict__ qtail, unsigned int* __restrict__ yb) {
    int i = blockIdx.x * blockDim.x + threadIdx.x;
    if (i < NSUBQ * 16) qtail[i] = 0;
    if (i < 32) yb[(size_t)DUMMY * 32 + i] = 0;
}

// Kernel 2 (fused, gemm blocks FIRST).
// Blocks [0, GEMM_BLOCKS): MFMA GEMM Y = X @ W, 2 adjacent 16-row strips per
// wave with all 16 x-loads batched (2x MLP vs R12's serial 1-strip wave).
// x loads NONTEMPORAL: the 51.2 MB read-once stream must not evict qbuild's
// queue-tail lines from L2 (R12: WRITE_SIZE 41 MB vs 17 expected = tail-line
// eviction storm re-created by the fused x stream).
// Blocks [GEMM_BLOCKS, +QB_BLOCKS): append edges to sub-queue (dst>>6, XCD).
__global__ __launch_bounds__(256) void fused_gemm_qbuild_kernel(
        const float* __restrict__ x, const float* __restrict__ W,
        const int* __restrict__ src, const int* __restrict__ dst,
        int* __restrict__ qtail, unsigned int* __restrict__ qbuf,
        unsigned short* __restrict__ ybu) {
    __shared__ unsigned int Wf[4 * 4 * 64 * 4];  // 16 KB

    if (blockIdx.x >= GEMM_BLOCKS) {
        // ---- qbuild role ----
        const int xcd = blockIdx.x & 7;  // blockIdx%8 -> XCD (perf-only heuristic)
        const int qb = blockIdx.x - GEMM_BLOCKS;
        for (int e = qb * 256 + threadIdx.x; e < N_EDGES; e += QB_BLOCKS * 256) {
            int d = __builtin_nontemporal_load(dst + e);
            int s = __builtin_nontemporal_load(src + e);
            int sq = ((d >> 6) << 3) | xcd;
            int pos = atomicAdd(&qtail[sq * 16], 1);
            if (pos < QCAP)
                qbuf[(size_t)sq * QCAP + pos] =
                    ((unsigned int)(d & 63) << 17) | (unsigned int)s;
        }
        return;
    }

    // ---- gemm role: Y = X @ W, bf16, packed so dword t = classes (t, t+32) ----
    for (int idx = threadIdx.x; idx < 4096; idx += 256) {
        int kk = idx >> 10, n = (idx >> 8) & 3, l = (idx >> 2) & 63, r = idx & 3;
        int k = kk * 32 + ((l >> 4) << 3) + 2 * r;
        int c = n * 16 + (l & 15);
        unsigned int lov = f32_to_bf16(W[k * CLASSES + c]);
        unsigned int hiv = f32_to_bf16(W[(k + 1) * CLASSES + c]);
        Wf[idx] = lov | (hiv << 16);
    }
    __syncthreads();

    const int wave = threadIdx.x >> 6;
    const int lane = threadIdx.x & 63;
    const int row_in = lane & 15;
    const int kb = (lane >> 4) << 3;

    const int widx = blockIdx.x * 4 + wave;  // pair index: strips 2w, 2w+1
    if (widx >= NSTRIP / 2) return;

    const float* xr0 = x + (size_t)(widx * 32 + row_in) * D_FEAT + kb;
    const float* xr1 = xr0 + 16 * D_FEAT;

    // batch all 16 loads (independent -> all in flight)
    fvec4 v[16];
#pragma unroll
    for (int kk = 0; kk < 4; ++kk) {
        v[kk * 2 + 0] = __builtin_nontemporal_load((const fvec4*)(xr0 + kk * 32));
        v[kk * 2 + 1] = __builtin_nontemporal_load((const fvec4*)(xr0 + kk * 32 + 4));
        v[8 + kk * 2 + 0] = __builtin_nontemporal_load((const fvec4*)(xr1 + kk * 32));
        v[8 + kk * 2 + 1] = __builtin_nontemporal_load((const fvec4*)(xr1 + kk * 32 + 4));
    }

    bf16x8 af0[4], af1[4];
#pragma unroll
    for (int kk = 0; kk < 4; ++kk) {
        fvec4 a = v[kk * 2], c = v[kk * 2 + 1];
        bf16x8 t0;
        t0[0] = (short)f32_to_bf16(a.x); t0[1] = (short)f32_to_bf16(a.y);
        t0[2] = (short)f32_to_bf16(a.z); t0[3] = (short)f32_to_bf16(a.w);
        t0[4] = (short)f32_to_bf16(c.x); t0[5] = (short)f32_to_bf16(c.y);
        t0[6] = (short)f32_to_bf16(c.z); t0[7] = (short)f32_to_bf16(c.w);
        af0[kk] = t0;
        fvec4 d = v[8 + kk * 2], e = v[8 + kk * 2 + 1];
        bf16x8 t1;
        t1[0] = (short)f32_to_bf16(d.x); t1[1] = (short)f32_to_bf16(d.y);
        t1[2] = (short)f32_to_bf16(d.z); t1[3] = (short)f32_to_bf16(d.w);
        t1[4] = (short)f32_to_bf16(e.x); t1[5] = (short)f32_to_bf16(e.y);
        t1[6] = (short)f32_to_bf16(e.z); t1[7] = (short)f32_to_bf16(e.w);
        af1[kk] = t1;
    }

    f32x4 acc0[4] = {{0.f,0.f,0.f,0.f},{0.f,0.f,0.f,0.f},{0.f,0.f,0.f,0.f},{0.f,0.f,0.f,0.f}};
    f32x4 acc1[4] = {{0.f,0.f,0.f,0.f},{0.f,0.f,0.f,0.f},{0.f,0.f,0.f,0.f},{0.f,0.f,0.f,0.f}};
#pragma unroll
    for (int n = 0; n < 4; ++n) {
#pragma unroll
        for (int kk = 0; kk < 4; ++kk) {
            bf16x8 bfr = *(const bf16x8*)&Wf[((kk * 4 + n) * 64 + lane) * 4];
            acc0[n] = __builtin_amdgcn_mfma_f32_16x16x32_bf16(af0[kk], bfr, acc0[n], 0, 0, 0);
            acc1[n] = __builtin_amdgcn_mfma_f32_16x16x32_bf16(af1[kk], bfr, acc1[n], 0, 0, 0);
        }
    }

    unsigned short* yr0 = ybu + (size_t)(widx * 2) * 16 * CLASSES;
    unsigned short* yr1 = yr0 + 16 * CLASSES;
#pragma unroll
    for (int n = 0; n < 4; ++n) {
        int c = n * 16 + (lane & 15);
        int pos = ((c & 31) << 1) + (c >> 5);
#pragma unroll
        for (int r = 0; r < 4; ++r) {
            yr0[((lane >> 4) * 4 + r) * CLASSES + pos] = f32_to_bf16(acc0[n][r]);
            yr1[((lane >> 4) * 4 + r) * CLASSES + pos] = f32_to_bf16(acc1[n][r]);
        }
    }
}

// Kernel 3: one block per 64-node partition. Stage queue entries into LDS,
// sort into CSR order (count + prefix-scan + scatter), then register gather:
// half-wave per node, 4 nodes interleaved, branch-free DUMMY padding.
__global__ __launch_bounds__(256) void accum_kernel(
        const unsigned int* __restrict__ yb, const int* __restrict__ qtail,
        const unsigned int* __restrict__ qbuf, const float* __restrict__ b,
        float* __restrict__ out) {
    __shared__ unsigned int ent[ENT_CAP];
    __shared__ int sorted_s[ENT_CAP];
    __shared__ int cnt_s[NPP], start_s[NPP], cursor_s[NPP];
    __shared__ int len8[8];

    const int tid = threadIdx.x;
    const int p = blockIdx.x;

    if (tid < NPP) cnt_s[tid] = 0;
    if (tid < 8) {
        int l = qtail[(p * 8 + tid) * 16];
        len8[tid] = min(l, QCAP);
    }
    __syncthreads();

    int lens[8], offs[8], tot = 0;
#pragma unroll
    for (int q = 0; q < 8; ++q) { lens[q] = len8[q]; offs[q] = tot; tot += lens[q]; }
    if (tot > ENT_CAP) tot = ENT_CAP;  // defensive; never hit

#pragma unroll
    for (int q = 0; q < 8; ++q) {
        const unsigned int* qsrc = qbuf + (size_t)(p * 8 + q) * QCAP;
        for (int i = tid; i < lens[q]; i += 256)
            if (offs[q] + i < ENT_CAP) ent[offs[q] + i] = qsrc[i];
    }
    __syncthreads();

    for (int i = tid; i < tot; i += 256) atomicAdd(&cnt_s[ent[i] >> 17], 1);
    __syncthreads();

    if (tid < 64) {  // wave 0: prefix scan over 64 node counts
        int v = cnt_s[tid];
        int incl = v;
#pragma unroll
        for (int o = 1; o < 64; o <<= 1) {
            int u = __shfl_up(incl, o, 64);
            if (tid >= o) incl += u;
        }
        start_s[tid] = incl - v;
        cursor_s[tid] = incl - v;
    }
    __syncthreads();

    for (int i = tid; i < tot; i += 256) {
        unsigned int e = ent[i];
        int pos = atomicAdd(&cursor_s[e >> 17], 1);
        sorted_s[pos] = (int)(e & 0x1FFFFu);
    }
    __syncthreads();

    const int hw = tid >> 5;   // half-wave 0..7
    const int t = tid & 31;
    const float b0 = b[t], b1 = b[t + 32];

#pragma unroll
    for (int rr = 0; rr < 2; ++rr) {
        const int r0 = hw * 8 + rr * 4;  // local nodes r0..r0+3
        int deg0 = cnt_s[r0], st0 = start_s[r0];
        int deg1 = cnt_s[r0 + 1], st1 = start_s[r0 + 1];
        int deg2 = cnt_s[r0 + 2], st2 = start_s[r0 + 2];
        int deg3 = cnt_s[r0 + 3], st3 = start_s[r0 + 3];
        int dmax = max(max(deg0, deg1), max(deg2, deg3));

        float2 a0 = {0.f, 0.f}, a1 = {0.f, 0.f}, a2 = {0.f, 0.f}, a3 = {0.f, 0.f};

        for (int cb = 0; cb < dmax; cb += 32) {
            int i0 = (cb + t < deg0) ? sorted_s[st0 + cb + t] : DUMMY;
            int i1 = (cb + t < deg1) ? sorted_s[st1 + cb + t] : DUMMY;
            int i2 = (cb + t < deg2) ? sorted_s[st2 + cb + t] : DUMMY;
            int i3 = (cb + t < deg3) ? sorted_s[st3 + cb + t] : DUMMY;
            int lim = min(32, dmax - cb);
#pragma unroll 4
            for (int j = 0; j < lim; ++j) {
                int s0 = __shfl(i0, j, 32);
                int s1 = __shfl(i1, j, 32);
                int s2 = __shfl(i2, j, 32);
                int s3 = __shfl(i3, j, 32);
                unsigned int y0 = yb[(size_t)s0 * 32 + t];
                unsigned int y1 = yb[(size_t)s1 * 32 + t];
                unsigned int y2 = yb[(size_t)s2 * 32 + t];
                unsigned int y3 = yb[(size_t)s3 * 32 + t];
                a0.x += bf16_lo(y0); a0.y += bf16_hi(y0);
                a1.x += bf16_lo(y1); a1.y += bf16_hi(y1);
                a2.x += bf16_lo(y2); a2.y += bf16_hi(y2);
                a3.x += bf16_lo(y3); a3.y += bf16_hi(y3);
            }
        }

#pragma unroll
        for (int k = 0; k < 4; ++k) {
            int node = p * NPP + r0 + k;
            if (node < N_NODES) {
                float2 a = (k == 0) ? a0 : (k == 1) ? a1 : (k == 2) ? a2 : a3;
                unsigned int u = yb[(size_t)node * 32 + t];
                out[(size_t)node * 64 + t] = a.x + bf16_lo(u) + b0;
                out[(size_t)node * 64 + t + 32] = a.y + bf16_hi(u) + b1;
            }
        }
    }
}

extern "C" void kernel_launch(void* const* d_in, const int* in_sizes, int n_in,
                              void* d_out, int out_size, void* d_ws, size_t ws_size,
                              hipStream_t stream) {
    const float* x = (const float*)d_in[0];
    const int* edge = (const int*)d_in[1];  // [2, N_EDGES] int32
    const float* W = (const float*)d_in[2];
    const float* b = (const float*)d_in[3];
    float* out = (float*)d_out;

    // workspace layout (~20 MB):
    int* qtail = (int*)d_ws;                              // 12504*16 ints = 800 KB
    unsigned int* qbuf = (unsigned int*)d_ws + 200192;    // 12504*128 dwords = 6.4 MB
    unsigned int* yb = qbuf + (size_t)NSUBQ * QCAP;       // 100001*32 dwords = 12.8 MB
    unsigned short* ybu = (unsigned short*)yb;

    const int* src = edge;
    const int* dst = edge + N_EDGES;

    zq_kernel<<<(NSUBQ * 16 + 255) / 256, 256, 0, stream>>>(qtail, yb);
    fused_gemm_qbuild_kernel<<<GEMM_BLOCKS + QB_BLOCKS, 256, 0, stream>>>(
        x, W, src, dst, qtail, qbuf, ybu);
    accum_kernel<<<NPART, 256, 0, stream>>>(yb, qtail, qbuf, b, out);
}